// Round 11
// baseline (231.136 us; speedup 1.0000x reference)
//
#include <hip/hip_runtime.h>
#include <hip/hip_bf16.h>

typedef __bf16 bf16_t;
typedef __bf16 bf16x8 __attribute__((ext_vector_type(8)));
typedef __bf16 bf16x4 __attribute__((ext_vector_type(4)));
typedef float  f32x4  __attribute__((ext_vector_type(4)));

#define NB  8
#define NC  256
#define NC8 32
#define NN  4096
#define PS  144   // P row stride in elements (288B = 18*16: b128-aligned, 72 dwords == 8 mod 32 -> row spreads banks)

#define MFMA16(a, b, c) __builtin_amdgcn_mfma_f32_16x16x32_bf16((a), (b), (c), 0, 0, 0)

// ---------------------------------------------------------------------------
// Weight panel layout: mat[R][256] -> element (o,k) at
//   panel[(o/16)*8 + k/32]*512 + (o&15)*32 + (k&31)
// Fragment load per wave (r*32 + 8q within panel) = contiguous 1KB.
// ---------------------------------------------------------------------------

// ---------------------------------------------------------------------------
// Kernel 0: fp32 -> bf16 + panelize all three weight matrices.
// ---------------------------------------------------------------------------
__global__ __launch_bounds__(256) void cvt_all(const float* __restrict__ wq,
                                               const float* __restrict__ wk,
                                               const float* __restrict__ wv,
                                               bf16_t* __restrict__ wqb,
                                               bf16_t* __restrict__ wkb,
                                               bf16_t* __restrict__ wvb) {
    int i = blockIdx.x * 256 + threadIdx.x;   // 0..20479
    const float* src; bf16_t* dst; int off;
    if (i < 2048)      { src = wq; dst = wqb; off = i; }
    else if (i < 4096) { src = wk; dst = wkb; off = i - 2048; }
    else               { src = wv; dst = wvb; off = i - 4096; }
    float4 v = reinterpret_cast<const float4*>(src)[off];
    const int e = off * 4;        // element offset in row-major [R][256]
    const int o = e >> 8;         // row
    const int k = e & 255;        // col (multiple of 4 -> one panel)
    const size_t d = (size_t)((o >> 4) * 8 + (k >> 5)) * 512 + (o & 15) * 32 + (k & 31);
    bf16x4 ov;
    ov[0] = (bf16_t)v.x; ov[1] = (bf16_t)v.y; ov[2] = (bf16_t)v.z; ov[3] = (bf16_t)v.w;
    *reinterpret_cast<bf16x4*>(dst + d) = ov;
}

// ---------------------------------------------------------------------------
// Kernel 1: proj3 (unchanged from round 10). LAUNCHED TWICE this round as a
// DIAGNOSTIC: proj3 is idempotent (pure function of x/weights), so the second
// launch adds exactly proj3's true duration to dur_us — finally measuring the
// proj cost that has never appeared in top-5.
// ---------------------------------------------------------------------------
__global__ __launch_bounds__(256) void proj3(const float* __restrict__ x,
                                             const bf16_t* __restrict__ wq,
                                             const float* __restrict__ bq,
                                             const bf16_t* __restrict__ wk,
                                             const float* __restrict__ bk,
                                             const bf16_t* __restrict__ wv,
                                             const float* __restrict__ bv,
                                             bf16_t* __restrict__ ft,
                                             bf16_t* __restrict__ gt,
                                             bf16_t* __restrict__ h) {
    __shared__ bf16_t xs[16][264];      // [n_loc][c], +8 pad

    const int bx = blockIdx.x;          // 2048
    const int b  = bx >> 8;
    const int n0 = (bx & 255) * 16;
    const int t  = threadIdx.x;         // = c row 0..255
    const int w    = t >> 6;
    const int lane = t & 63;
    const int q    = lane >> 4;
    const int r    = lane & 15;

    // ---- load x[b][c=t][n0..n0+15]: 4 float4 (one 64B cacheline, all used)
    const float* xp = x + ((size_t)b * NC + t) * NN + n0;
    float4 v0 = *reinterpret_cast<const float4*>(xp + 0);
    float4 v1 = *reinterpret_cast<const float4*>(xp + 4);
    float4 v2 = *reinterpret_cast<const float4*>(xp + 8);
    float4 v3 = *reinterpret_cast<const float4*>(xp + 12);
    float vv[16] = {v0.x, v0.y, v0.z, v0.w, v1.x, v1.y, v1.z, v1.w,
                    v2.x, v2.y, v2.z, v2.w, v3.x, v3.y, v3.z, v3.w};
#pragma unroll
    for (int n = 0; n < 16; ++n) xs[n][t] = (bf16_t)vv[n];
    __syncthreads();

    const int fo = r * 32 + 8 * q;      // within-panel fragment offset
    const bf16_t* arow = &xs[r][0];     // act fragment base (+32kp+8q)

    // ---- q/k projections (wave 0 = q, wave 1 = k); o on 4q+i, n on r
    if (w < 2) {
        const bf16_t* W  = (w == 0) ? wq : wk;
        f32x4 acc[2];
        acc[0] = (f32x4){0.f, 0.f, 0.f, 0.f};
        acc[1] = (f32x4){0.f, 0.f, 0.f, 0.f};
#pragma unroll
        for (int kp = 0; kp < 8; ++kp) {
            bf16x8 a = *reinterpret_cast<const bf16x8*>(arow + 32 * kp + 8 * q);
#pragma unroll
            for (int ot = 0; ot < 2; ++ot) {
                bf16x8 wf = *reinterpret_cast<const bf16x8*>(W + (ot * 8 + kp) * 512 + fo);
                acc[ot] = MFMA16(wf, a, acc[ot]);
            }
        }
        const float* Bv = (w == 0) ? bq : bk;
        bf16_t* dst = ((w == 0) ? ft : gt) + ((size_t)b * NN + n0 + r) * NC8;
#pragma unroll
        for (int ot = 0; ot < 2; ++ot) {
            const int o4 = 16 * ot + 4 * q;
            float4 b4 = *reinterpret_cast<const float4*>(Bv + o4);
            bf16x4 p;
            p[0] = (bf16_t)(acc[ot][0] + b4.x); p[1] = (bf16_t)(acc[ot][1] + b4.y);
            p[2] = (bf16_t)(acc[ot][2] + b4.z); p[3] = (bf16_t)(acc[ot][3] + b4.w);
            *reinterpret_cast<bf16x4*>(dst + o4) = p;
        }
    }

    // ---- v projection: wave w owns c-tiles 4w..4w+3; n on 4q+i, c on r
    f32x4 vacc[4];
#pragma unroll
    for (int i = 0; i < 4; ++i) vacc[i] = (f32x4){0.f, 0.f, 0.f, 0.f};

#pragma unroll
    for (int kp = 0; kp < 8; ++kp) {
        bf16x8 a = *reinterpret_cast<const bf16x8*>(arow + 32 * kp + 8 * q);
#pragma unroll
        for (int i = 0; i < 4; ++i) {
            bf16x8 wf = *reinterpret_cast<const bf16x8*>(
                wv + (size_t)((4 * w + i) * 8 + kp) * 512 + fo);
            vacc[i] = MFMA16(a, wf, vacc[i]);
        }
    }
    {
        const int n32 = n0 >> 5;
        const int dn0 = (n0 & 16) + 4 * q;
#pragma unroll
        for (int i = 0; i < 4; ++i) {
            const int c = 16 * (4 * w + i) + r;
            const float bvc = bv[c];
            bf16x4 p;
            p[0] = (bf16_t)(vacc[i][0] + bvc);
            p[1] = (bf16_t)(vacc[i][1] + bvc);
            p[2] = (bf16_t)(vacc[i][2] + bvc);
            p[3] = (bf16_t)(vacc[i][3] + bvc);
            *reinterpret_cast<bf16x4*>(
                h + (((size_t)b * 128 + n32) * NC + c) * 32 + dn0) = p;
        }
    }
}

// ---------------------------------------------------------------------------
// Kernel 2: attention. ONLY change vs round 6/10: P row stride 128 -> 144
// elements (288B). Old stride 256B == 0 mod 128B meant every pf ds_read_b128
// had all 16 rows bank-aliased (only the 8 XOR slots spread -> ~4-8-way
// conflicts, SQ_LDS_BANK_CONFLICT 10.5M ~= 19% of wall). 288B == 8 dwords
// mod 32 banks: bank group g = (2r + slot) mod 8 is a bijection over r=0..7
// for every slot constant -> only the free r/r+8 2-way pair remains.
// ---------------------------------------------------------------------------
#define O_STEP(HU, HL, KC, LOFF)                                               \
    {                                                                          \
        _Pragma("unroll")                                                      \
        for (int ct = 0; ct < 2; ++ct)                                         \
            HL[ct] = *reinterpret_cast<const bf16x8*>(                         \
                hrow[ct] + (size_t)(LOFF) * 256);                              \
        bf16x8 pf[4];                                                          \
        _Pragma("unroll")                                                      \
        for (int mt = 0; mt < 4; ++mt) {                                       \
            const int row = 16 * mt + r;                                       \
            pf[mt] = *reinterpret_cast<const bf16x8*>(                         \
                &Pb[row * PS + (((4 * (KC) + q) ^ rq) << 3)]);                 \
        }                                                                      \
        _Pragma("unroll")                                                      \
        for (int ct = 0; ct < 2; ++ct)                                         \
            _Pragma("unroll")                                                  \
            for (int mt = 0; mt < 4; ++mt)                                     \
                acc[ct][mt] = MFMA16(HU[ct], pf[mt], acc[ct][mt]);             \
    }

__global__ __launch_bounds__(512, 4) void attn(const bf16_t* __restrict__ ft,
                                               const bf16_t* __restrict__ gt,
                                               const bf16_t* __restrict__ h,
                                               float* __restrict__ out) {
    __shared__ bf16_t P[2 * 64 * PS];   // 36.9 KB, double buffered
    __shared__ float  l_lds[64];

    const int bx = blockIdx.x;       // 512
    const int b  = bx & 7;           // XCD pin
    const int m0 = (bx >> 3) * 64;
    const int tid  = threadIdx.x;
    const int w    = tid >> 6;       // 0..7
    const int lane = tid & 63;
    const int q    = lane >> 4;
    const int r    = lane & 15;
    const int rq   = r & 7;

    if (tid < 64) l_lds[tid] = 0.f;

    bf16x8 qf[4];
#pragma unroll
    for (int mt = 0; mt < 4; ++mt)
        qf[mt] = *reinterpret_cast<const bf16x8*>(
            gt + ((size_t)b * NN + m0 + 16 * mt + r) * NC8 + 8 * q);

    f32x4 acc[2][4];
#pragma unroll
    for (int ct = 0; ct < 2; ++ct)
#pragma unroll
        for (int mt = 0; mt < 4; ++mt) acc[ct][mt] = (f32x4){0.f, 0.f, 0.f, 0.f};
    float lp[4] = {0.f, 0.f, 0.f, 0.f};

    const bf16_t* fb = ft + (size_t)b * NN * NC8;
    const bf16_t* hb = h + (size_t)b * 128 * NC * 32;   // h32[b]...
    const f32x4 zero = (f32x4){0.f, 0.f, 0.f, 0.f};

    const bf16_t* hrow[2];
#pragma unroll
    for (int ct = 0; ct < 2; ++ct)
        hrow[ct] = hb + (size_t)(32 * w + 16 * ct + r) * 32 + 8 * q;
    const bf16_t* fptr = fb + (size_t)(16 * w + r) * NC8 + 8 * q;

    // ---- prologue: s(chunk 0); h0 = chunk0/kc0
    f32x4 s[4];
    {
        bf16x8 a0 = *reinterpret_cast<const bf16x8*>(fptr);
#pragma unroll
        for (int mt = 0; mt < 4; ++mt) s[mt] = MFMA16(a0, qf[mt], zero);
    }
    bf16x8 h0[2], h1[2];
#pragma unroll
    for (int ct = 0; ct < 2; ++ct)
        h0[ct] = *reinterpret_cast<const bf16x8*>(hrow[ct]);

    for (int ii = 0; ii < 32; ++ii) {
        bf16_t* Pb = &P[(ii & 1) * 64 * PS];
        const int nb = ii * 128;
        const int nld = (ii + 1 < 32 ? ii + 1 : 31) * 128;

        // ---- issue af load for chunk ii+1 FIRST (max slack, crosses barrier)
        bf16x8 af0 = *reinterpret_cast<const bf16x8*>(fptr + (size_t)nld * NC8);

        // ---- exp + write P[cur]
#pragma unroll
        for (int mt = 0; mt < 4; ++mt) {
            float e0 = __expf(s[mt][0]);
            float e1 = __expf(s[mt][1]);
            float e2 = __expf(s[mt][2]);
            float e3 = __expf(s[mt][3]);
            lp[mt] += (e0 + e1) + (e2 + e3);
            bf16x4 pv;
            pv[0] = (bf16_t)e0; pv[1] = (bf16_t)e1; pv[2] = (bf16_t)e2; pv[3] = (bf16_t)e3;
            const int row  = 16 * mt + r;
            const int nblk = 2 * w + (q >> 1);
            *reinterpret_cast<bf16x4*>(
                &Pb[row * PS + ((nblk ^ rq) << 3) + 4 * (q & 1)]) = pv;
        }

        // ---- NON-DRAINING barrier: order LDS only; VMEM prefetch survives
        asm volatile("s_waitcnt lgkmcnt(0)" ::: "memory");
        __builtin_amdgcn_sched_barrier(0);
        __builtin_amdgcn_s_barrier();
        __builtin_amdgcn_sched_barrier(0);

        // ---- O phase: 4 k-chunks of 32 n, h ping-pong one chunk ahead
        const int nbn = (ii + 1 < 32 ? nb + 128 : nb);
        __builtin_amdgcn_s_setprio(1);
        O_STEP(h0, h1, 0, nb + 32);
        O_STEP(h1, h0, 1, nb + 64);
        O_STEP(h0, h1, 2, nb + 96);
        O_STEP(h1, h0, 3, nbn);

        // ---- S(ii+1)
#pragma unroll
        for (int mt = 0; mt < 4; ++mt) s[mt] = MFMA16(af0, qf[mt], zero);
        __builtin_amdgcn_s_setprio(0);
    }

    // ---- reduce l partials
    __syncthreads();
#pragma unroll
    for (int mt = 0; mt < 4; ++mt) {
        float v = lp[mt];
        v += __shfl_xor(v, 16);
        v += __shfl_xor(v, 32);
        if (q == 0) atomicAdd(&l_lds[16 * mt + r], v);
    }
    __syncthreads();

    // ---- epilogue: out[b][c][m] = acc / l[m]
#pragma unroll
    for (int ct = 0; ct < 2; ++ct) {
#pragma unroll
        for (int mt = 0; mt < 4; ++mt) {
            const int m = m0 + 16 * mt + r;
            const float linv = 1.0f / l_lds[16 * mt + r];
#pragma unroll
            for (int i = 0; i < 4; ++i) {
                const int c = 32 * w + 16 * ct + 4 * q + i;
                out[((size_t)b * NC + c) * NN + m] = acc[ct][mt][i] * linv;
            }
        }
    }
}

extern "C" void kernel_launch(void* const* d_in, const int* in_sizes, int n_in,
                              void* d_out, int out_size, void* d_ws, size_t ws_size,
                              hipStream_t stream) {
    const float* x  = (const float*)d_in[0];
    const float* wq = (const float*)d_in[1];
    const float* bq = (const float*)d_in[2];
    const float* wk = (const float*)d_in[3];
    const float* bk = (const float*)d_in[4];
    const float* wv = (const float*)d_in[5];
    const float* bv = (const float*)d_in[6];
    float* out = (float*)d_out;

    bf16_t* ft  = (bf16_t*)d_ws;                     // [B][N][32]
    bf16_t* gt  = ft + (size_t)NB * NN * NC8;        // [B][N][32]
    bf16_t* hb  = gt + (size_t)NB * NN * NC8;        // h32: [B][N/32][C][32]
    bf16_t* wqb = hb + (size_t)NB * NC * NN;         // 16 panels
    bf16_t* wkb = wqb + (size_t)NC8 * NC;            // 16 panels
    bf16_t* wvb = wkb + (size_t)NC8 * NC;            // 128 panels

    cvt_all<<<80, 256, 0, stream>>>(wq, wk, wv, wqb, wkb, wvb);
    // DIAGNOSTIC (this round only): proj3 launched twice. It is idempotent,
    // so the second launch adds exactly its true duration to dur_us --
    // measuring the proj cost that has never appeared in the top-5 counters.
    proj3<<<NB * (NN / 16), 256, 0, stream>>>(x, wqb, bq, wkb, bk, wvb, bv, ft, gt, hb);
    proj3<<<NB * (NN / 16), 256, 0, stream>>>(x, wqb, bq, wkb, bk, wvb, bv, ft, gt, hb);
    attn<<<NB * (NN / 64), 512, 0, stream>>>(ft, gt, hb, out);
}

// Round 12
// 184.593 us; speedup vs baseline: 1.2521x; 1.2521x over previous
//
#include <hip/hip_runtime.h>
#include <hip/hip_bf16.h>

typedef __bf16 bf16_t;
typedef __bf16 bf16x8 __attribute__((ext_vector_type(8)));
typedef __bf16 bf16x4 __attribute__((ext_vector_type(4)));
typedef float  f32x4  __attribute__((ext_vector_type(4)));

#define NB  8
#define NC  256
#define NC8 32
#define NN  4096
#define XS  264   // xs row stride (528B = 33*16, b128-aligned)

#define MFMA16(a, b, c) __builtin_amdgcn_mfma_f32_16x16x32_bf16((a), (b), (c), 0, 0, 0)

// ---------------------------------------------------------------------------
// Weight panel layout: mat[R][256] -> element (o,k) at
//   panel[(o/16)*8 + k/32]*512 + (o&15)*32 + (k&31)
// Fragment load per wave (r*32 + 8q within panel) = contiguous 1KB.
// ---------------------------------------------------------------------------

// ---------------------------------------------------------------------------
// Kernel 0: fp32 -> bf16 + panelize all three weight matrices.
// ---------------------------------------------------------------------------
__global__ __launch_bounds__(256) void cvt_all(const float* __restrict__ wq,
                                               const float* __restrict__ wk,
                                               const float* __restrict__ wv,
                                               bf16_t* __restrict__ wqb,
                                               bf16_t* __restrict__ wkb,
                                               bf16_t* __restrict__ wvb) {
    int i = blockIdx.x * 256 + threadIdx.x;   // 0..20479
    const float* src; bf16_t* dst; int off;
    if (i < 2048)      { src = wq; dst = wqb; off = i; }
    else if (i < 4096) { src = wk; dst = wkb; off = i - 2048; }
    else               { src = wv; dst = wvb; off = i - 4096; }
    float4 v = reinterpret_cast<const float4*>(src)[off];
    const int e = off * 4;        // element offset in row-major [R][256]
    const int o = e >> 8;         // row
    const int k = e & 255;        // col (multiple of 4 -> one panel)
    const size_t d = (size_t)((o >> 4) * 8 + (k >> 5)) * 512 + (o & 15) * 32 + (k & 31);
    bf16x4 ov;
    ov[0] = (bf16_t)v.x; ov[1] = (bf16_t)v.y; ov[2] = (bf16_t)v.z; ov[3] = (bf16_t)v.w;
    *reinterpret_cast<bf16x4*>(dst + d) = ov;
}

// ---------------------------------------------------------------------------
// Kernel 1: proj2 (round-9 version, best measured proj ~21us): fused
// transpose + q/k/v projections, panelized weights, swapped MFMA operand
// order -> all epilogue stores bf16x4.
// ---------------------------------------------------------------------------
__global__ __launch_bounds__(256) void proj2(const float* __restrict__ x,
                                             const bf16_t* __restrict__ wq,
                                             const float* __restrict__ bq,
                                             const bf16_t* __restrict__ wk,
                                             const float* __restrict__ bk,
                                             const bf16_t* __restrict__ wv,
                                             const float* __restrict__ bv,
                                             bf16_t* __restrict__ ft,
                                             bf16_t* __restrict__ gt,
                                             bf16_t* __restrict__ h) {
    __shared__ bf16_t tile[64][72];
    __shared__ bf16_t xs[64 * XS];      // [n_loc][c]

    const int bx = blockIdx.x;          // 512
    const int b  = bx >> 6;
    const int n0 = (bx & 63) * 64;
    const int t  = threadIdx.x;
    const int w    = t >> 6;
    const int lane = t & 63;
    const int q    = lane >> 4;
    const int r    = lane & 15;

    const int cl  = t >> 4;
    const int nl  = (t & 15) * 4;
    const int nb_ = t >> 3;
    const int cl2 = (t & 7) * 8;

    // ---- hoisted x loads: all 16 in flight at once
    float4 xv[16];
#pragma unroll
    for (int cp = 0; cp < 4; ++cp)
#pragma unroll
        for (int p = 0; p < 4; ++p)
            xv[4 * cp + p] = *reinterpret_cast<const float4*>(
                x + ((size_t)b * NC + 64 * cp + cl + 16 * p) * NN + n0 + nl);

    // ---- early weight prefetch (kp=0 fragments) — hides under transpose
    const int fo = r * 32 + 8 * q;      // within-panel fragment offset
    bf16x8 fq_c[2], fk_c[2], wv_c[4];
#pragma unroll
    for (int ot = 0; ot < 2; ++ot) {
        fq_c[ot] = *reinterpret_cast<const bf16x8*>(wq + ot * 4096 + fo);
        fk_c[ot] = *reinterpret_cast<const bf16x8*>(wk + ot * 4096 + fo);
    }
#pragma unroll
    for (int ct = 0; ct < 4; ++ct)
        wv_c[ct] = *reinterpret_cast<const bf16x8*>(
            wv + (size_t)w * 4096 + (size_t)ct * 16384 + fo);

    // ---- two-phase LDS transpose (proven)
    for (int cp = 0; cp < 4; ++cp) {
#pragma unroll
        for (int p = 0; p < 4; ++p) {
            const int cc = cl + 16 * p;
            float4 v = xv[4 * cp + p];
            bf16x4 bv4;
            bv4[0] = (bf16_t)v.x; bv4[1] = (bf16_t)v.y; bv4[2] = (bf16_t)v.z; bv4[3] = (bf16_t)v.w;
            *reinterpret_cast<bf16x4*>(&tile[cc][nl]) = bv4;
        }
        __syncthreads();
#pragma unroll
        for (int p = 0; p < 2; ++p) {
            const int nn = nb_ + 32 * p;
            bf16x8 v;
            for (int i = 0; i < 8; ++i) v[i] = tile[cl2 + i][nn];
            *reinterpret_cast<bf16x8*>(&xs[nn * XS + 64 * cp + cl2]) = v;
        }
        __syncthreads();
    }

    // ---- q/k projections: wave w owns n-rows [16w,16w+16); n on r-axis
    {
        const bf16_t* xrow = &xs[(16 * w + r) * XS];
        f32x4 accq[2], acck[2];
        for (int ot = 0; ot < 2; ++ot) {
            accq[ot] = (f32x4){0.f, 0.f, 0.f, 0.f};
            acck[ot] = (f32x4){0.f, 0.f, 0.f, 0.f};
        }
        bf16x8 a_c = *reinterpret_cast<const bf16x8*>(xrow + 8 * q);
        for (int kp = 0; kp < 8; ++kp) {
            const int kn = (kp + 1 < 8) ? kp + 1 : 0;
            bf16x8 a_n = *reinterpret_cast<const bf16x8*>(xrow + kn * 32 + 8 * q);
            bf16x8 fq_n[2], fk_n[2];
#pragma unroll
            for (int ot = 0; ot < 2; ++ot) {
                fq_n[ot] = *reinterpret_cast<const bf16x8*>(wq + ot * 4096 + kn * 512 + fo);
                fk_n[ot] = *reinterpret_cast<const bf16x8*>(wk + ot * 4096 + kn * 512 + fo);
            }
#pragma unroll
            for (int ot = 0; ot < 2; ++ot) {
                accq[ot] = MFMA16(fq_c[ot], a_c, accq[ot]);   // o on 4q+i, n on r
                acck[ot] = MFMA16(fk_c[ot], a_c, acck[ot]);
            }
            a_c = a_n;
#pragma unroll
            for (int ot = 0; ot < 2; ++ot) { fq_c[ot] = fq_n[ot]; fk_c[ot] = fk_n[ot]; }
        }
        const int n = n0 + 16 * w + r;
#pragma unroll
        for (int ot = 0; ot < 2; ++ot) {
            const int o4 = 16 * ot + 4 * q;
            float4 b4q = *reinterpret_cast<const float4*>(bq + o4);
            float4 b4k = *reinterpret_cast<const float4*>(bk + o4);
            bf16x4 pq, pk;
            pq[0] = (bf16_t)(accq[ot][0] + b4q.x); pq[1] = (bf16_t)(accq[ot][1] + b4q.y);
            pq[2] = (bf16_t)(accq[ot][2] + b4q.z); pq[3] = (bf16_t)(accq[ot][3] + b4q.w);
            pk[0] = (bf16_t)(acck[ot][0] + b4k.x); pk[1] = (bf16_t)(acck[ot][1] + b4k.y);
            pk[2] = (bf16_t)(acck[ot][2] + b4k.z); pk[3] = (bf16_t)(acck[ot][3] + b4k.w);
            *reinterpret_cast<bf16x4*>(ft + ((size_t)b * NN + n) * NC8 + o4) = pq;
            *reinterpret_cast<bf16x4*>(gt + ((size_t)b * NN + n) * NC8 + o4) = pk;
        }
    }

    // ---- v projection: c = 64ct+16w+r (B-side), n = 16nt+4q+i (A-side)
    f32x4 vacc[4][4];
    for (int ct = 0; ct < 4; ++ct)
        for (int nt = 0; nt < 4; ++nt) vacc[ct][nt] = (f32x4){0.f, 0.f, 0.f, 0.f};

    bf16x8 bfr_c[4];
#pragma unroll
    for (int nt = 0; nt < 4; ++nt)
        bfr_c[nt] = *reinterpret_cast<const bf16x8*>(&xs[(16 * nt + r) * XS + 8 * q]);

    for (int kp = 0; kp < 8; ++kp) {
        const int kn = (kp + 1 < 8) ? kp + 1 : 0;
        bf16x8 wv_n[4], bfr_n[4];
#pragma unroll
        for (int ct = 0; ct < 4; ++ct)
            wv_n[ct] = *reinterpret_cast<const bf16x8*>(
                wv + (size_t)w * 4096 + (size_t)ct * 16384 + kn * 512 + fo);
#pragma unroll
        for (int nt = 0; nt < 4; ++nt)
            bfr_n[nt] = *reinterpret_cast<const bf16x8*>(&xs[(16 * nt + r) * XS + kn * 32 + 8 * q]);
#pragma unroll
        for (int ct = 0; ct < 4; ++ct)
#pragma unroll
            for (int nt = 0; nt < 4; ++nt)
                vacc[ct][nt] = MFMA16(bfr_c[nt], wv_c[ct], vacc[ct][nt]);
#pragma unroll
        for (int ct = 0; ct < 4; ++ct) wv_c[ct] = wv_n[ct];
#pragma unroll
        for (int nt = 0; nt < 4; ++nt) bfr_c[nt] = bfr_n[nt];
    }

    // ---- h epilogue: h32[b][n/32][c][n%32], bf16x4 stores (n contig per thread)
#pragma unroll
    for (int ct = 0; ct < 4; ++ct) {
        const int c = 64 * ct + 16 * w + r;
        const float bvc = bv[c];
#pragma unroll
        for (int nt = 0; nt < 4; ++nt) {
            const int n32 = (n0 >> 5) + (nt >> 1);
            const int dn0 = 16 * (nt & 1) + 4 * q;
            bf16x4 pv;
            pv[0] = (bf16_t)(vacc[ct][nt][0] + bvc);
            pv[1] = (bf16_t)(vacc[ct][nt][1] + bvc);
            pv[2] = (bf16_t)(vacc[ct][nt][2] + bvc);
            pv[3] = (bf16_t)(vacc[ct][nt][3] + bvc);
            *reinterpret_cast<bf16x4*>(
                h + (((size_t)b * 128 + n32) * NC + c) * 32 + dn0) = pv;
        }
    }
}

// ---------------------------------------------------------------------------
// Kernel 2: attention. vs round 6 base (P stride back to 128):
//   * h prefetch deepened to 2 chunks ahead: 4-buffer rotation h0..h3
//     (use h[s], load h[(s+2)%4]) -> 310+ cyc slack vs L2 latency ~200-450
//     (was 1 step = 155 cyc, exposed).
//   * pf double-buffered: pf for step s+1 issued during step s's MFMAs
//     (was JIT -> ~120 cyc ds latency exposed per step; now only step 0 pays).
//   * S-MFMAs moved up (after O1) -> next iter's exp has 2 O_STEPs of slack.
// ---------------------------------------------------------------------------
#define PF_LOAD(PF, KC)                                                        \
    _Pragma("unroll")                                                          \
    for (int mt = 0; mt < 4; ++mt) {                                           \
        const int row = 16 * mt + r;                                           \
        PF[mt] = *reinterpret_cast<const bf16x8*>(                             \
            &Pb[(row << 7) + (((4 * (KC) + q) ^ rq) << 3)]);                   \
    }

#define MM8(HU, PF)                                                            \
    _Pragma("unroll")                                                          \
    for (int ct = 0; ct < 2; ++ct)                                             \
        _Pragma("unroll")                                                      \
        for (int mt = 0; mt < 4; ++mt)                                         \
            acc[ct][mt] = MFMA16(HU[ct], PF[mt], acc[ct][mt]);

#define HLD(HD, LOFF)                                                          \
    _Pragma("unroll")                                                          \
    for (int ct = 0; ct < 2; ++ct)                                             \
        HD[ct] = *reinterpret_cast<const bf16x8*>(                             \
            hrow[ct] + (size_t)(LOFF) * 256);

__global__ __launch_bounds__(512, 4) void attn(const bf16_t* __restrict__ ft,
                                               const bf16_t* __restrict__ gt,
                                               const bf16_t* __restrict__ h,
                                               float* __restrict__ out) {
    __shared__ bf16_t P[2 * 64 * 128];   // 32 KB, double buffered
    __shared__ float  l_lds[64];

    const int bx = blockIdx.x;       // 512
    const int b  = bx & 7;           // XCD pin
    const int m0 = (bx >> 3) * 64;
    const int tid  = threadIdx.x;
    const int w    = tid >> 6;       // 0..7
    const int lane = tid & 63;
    const int q    = lane >> 4;
    const int r    = lane & 15;
    const int rq   = r & 7;

    if (tid < 64) l_lds[tid] = 0.f;

    bf16x8 qf[4];
#pragma unroll
    for (int mt = 0; mt < 4; ++mt)
        qf[mt] = *reinterpret_cast<const bf16x8*>(
            gt + ((size_t)b * NN + m0 + 16 * mt + r) * NC8 + 8 * q);

    f32x4 acc[2][4];
#pragma unroll
    for (int ct = 0; ct < 2; ++ct)
#pragma unroll
        for (int mt = 0; mt < 4; ++mt) acc[ct][mt] = (f32x4){0.f, 0.f, 0.f, 0.f};
    float lp[4] = {0.f, 0.f, 0.f, 0.f};

    const bf16_t* fb = ft + (size_t)b * NN * NC8;
    const bf16_t* hb = h + (size_t)b * 128 * NC * 32;   // h32[b]...
    const f32x4 zero = (f32x4){0.f, 0.f, 0.f, 0.f};

    const bf16_t* hrow[2];
#pragma unroll
    for (int ct = 0; ct < 2; ++ct)
        hrow[ct] = hb + (size_t)(32 * w + 16 * ct + r) * 32 + 8 * q;
    const bf16_t* fptr = fb + (size_t)(16 * w + r) * NC8 + 8 * q;

    // ---- prologue: s(chunk 0); h0/h1 = chunk0 kc0/kc1
    f32x4 s[4];
    {
        bf16x8 a0 = *reinterpret_cast<const bf16x8*>(fptr);
#pragma unroll
        for (int mt = 0; mt < 4; ++mt) s[mt] = MFMA16(a0, qf[mt], zero);
    }
    bf16x8 h0[2], h1[2], h2[2], h3[2];
    HLD(h0, 0);
    HLD(h1, 32);

    for (int ii = 0; ii < 32; ++ii) {
        bf16_t* Pb = &P[(ii & 1) << 13];
        const int nb   = ii * 128;
        const int nld  = (ii + 1 < 32 ? ii + 1 : 31) * 128;
        const int nkc0 = (ii + 1 < 32 ? nb + 128 : nb);        // next chunk kc0
        const int nkc1 = (ii + 1 < 32 ? nb + 160 : nb + 32);   // next chunk kc1

        // ---- issue af load for chunk ii+1 FIRST (max slack, crosses barrier)
        bf16x8 af0 = *reinterpret_cast<const bf16x8*>(fptr + (size_t)nld * NC8);

        // ---- exp + write P[cur]
#pragma unroll
        for (int mt = 0; mt < 4; ++mt) {
            float e0 = __expf(s[mt][0]);
            float e1 = __expf(s[mt][1]);
            float e2 = __expf(s[mt][2]);
            float e3 = __expf(s[mt][3]);
            lp[mt] += (e0 + e1) + (e2 + e3);
            bf16x4 pv;
            pv[0] = (bf16_t)e0; pv[1] = (bf16_t)e1; pv[2] = (bf16_t)e2; pv[3] = (bf16_t)e3;
            const int row  = 16 * mt + r;
            const int nblk = 2 * w + (q >> 1);
            *reinterpret_cast<bf16x4*>(
                &Pb[(row << 7) + ((nblk ^ rq) << 3) + 4 * (q & 1)]) = pv;
        }

        // ---- NON-DRAINING barrier: order LDS only; VMEM prefetch survives
        asm volatile("s_waitcnt lgkmcnt(0)" ::: "memory");
        __builtin_amdgcn_sched_barrier(0);
        __builtin_amdgcn_s_barrier();
        __builtin_amdgcn_sched_barrier(0);

        // ---- O phase: 4 steps; h depth-2 rotation, pf double-buffer
        __builtin_amdgcn_s_setprio(1);
        bf16x8 pfA[4], pfB[4];
        PF_LOAD(pfA, 0);
        HLD(h2, nb + 64);   PF_LOAD(pfB, 1);   MM8(h0, pfA);
        HLD(h3, nb + 96);   PF_LOAD(pfA, 2);   MM8(h1, pfB);
        // ---- S(ii+1) moved up: 2 O_STEPs of slack before next-iter exp
#pragma unroll
        for (int mt = 0; mt < 4; ++mt) s[mt] = MFMA16(af0, qf[mt], zero);
        HLD(h0, nkc0);      PF_LOAD(pfB, 3);   MM8(h2, pfA);
        HLD(h1, nkc1);                         MM8(h3, pfB);
        __builtin_amdgcn_s_setprio(0);
    }

    // ---- reduce l partials
    __syncthreads();
#pragma unroll
    for (int mt = 0; mt < 4; ++mt) {
        float v = lp[mt];
        v += __shfl_xor(v, 16);
        v += __shfl_xor(v, 32);
        if (q == 0) atomicAdd(&l_lds[16 * mt + r], v);
    }
    __syncthreads();

    // ---- epilogue: out[b][c][m] = acc / l[m]
#pragma unroll
    for (int ct = 0; ct < 2; ++ct) {
#pragma unroll
        for (int mt = 0; mt < 4; ++mt) {
            const int m = m0 + 16 * mt + r;
            const float linv = 1.0f / l_lds[16 * mt + r];
#pragma unroll
            for (int i = 0; i < 4; ++i) {
                const int c = 32 * w + 16 * ct + 4 * q + i;
                out[((size_t)b * NC + c) * NN + m] = acc[ct][mt][i] * linv;
            }
        }
    }
}

extern "C" void kernel_launch(void* const* d_in, const int* in_sizes, int n_in,
                              void* d_out, int out_size, void* d_ws, size_t ws_size,
                              hipStream_t stream) {
    const float* x  = (const float*)d_in[0];
    const float* wq = (const float*)d_in[1];
    const float* bq = (const float*)d_in[2];
    const float* wk = (const float*)d_in[3];
    const float* bk = (const float*)d_in[4];
    const float* wv = (const float*)d_in[5];
    const float* bv = (const float*)d_in[6];
    float* out = (float*)d_out;

    bf16_t* ft  = (bf16_t*)d_ws;                     // [B][N][32]
    bf16_t* gt  = ft + (size_t)NB * NN * NC8;        // [B][N][32]
    bf16_t* hb  = gt + (size_t)NB * NN * NC8;        // h32: [B][N/32][C][32]
    bf16_t* wqb = hb + (size_t)NB * NC * NN;         // 16 panels
    bf16_t* wkb = wqb + (size_t)NC8 * NC;            // 16 panels
    bf16_t* wvb = wkb + (size_t)NC8 * NC;            // 128 panels

    cvt_all<<<80, 256, 0, stream>>>(wq, wk, wv, wqb, wkb, wvb);
    proj2<<<NB * (NN / 64), 256, 0, stream>>>(x, wqb, bq, wkb, bk, wvb, bv, ft, gt, hb);
    attn<<<NB * (NN / 64), 512, 0, stream>>>(ft, gt, hb, out);
}